// Round 7
// baseline (1984.130 us; speedup 1.0000x reference)
//
#include <hip/hip_runtime.h>

#define KNN    8
#define GD     48
#define NCELL  (GD*GD*GD)
#define BLO    (-45.0f)
#define BW     1.875f
#define BINV   (1.0f / 1.875f)
#define BHI    (BLO + GD * BW)
#define EPSW   1e-8f
#define BIGF   3.4e38f

typedef unsigned long long u64;
typedef unsigned int u32;

#define KEY_INIT 0x7F7FFFFFFFFFFFFFull

// Sorted-descending top-8 of u64 keys (key = (f32bits(d2c)<<32)|idx).
// Lexicographic (d2, idx) == reference top_k order. Proven R4/R5/R6.
__device__ __forceinline__ void ins8(u64 key, u64 bk[KNN]) {
    if (key < bk[0]) {
        bk[0] = key;
#pragma unroll
        for (int t = 0; t < KNN - 1; t++) {
            if (bk[t] < bk[t + 1]) { u64 tmp = bk[t]; bk[t] = bk[t + 1]; bk[t + 1] = tmp; }
        }
    }
}

__device__ __forceinline__ int cellc(float x) {
    int c = (int)floorf((x - BLO) * BINV);
    return min(max(c, 0), GD - 1);
}

// ---- K1: count refs + queries per (clamped) cell ----
__global__ __launch_bounds__(256) void count_kern(const float* __restrict__ r,
        const float* __restrict__ q, int M, int N,
        int* __restrict__ rcnt, int* __restrict__ qcnt) {
    int t = blockIdx.x * 256 + threadIdx.x;
    if (t < M) {
        int c = (cellc(r[3*t+2]) * GD + cellc(r[3*t+1])) * GD + cellc(r[3*t]);
        atomicAdd(&rcnt[c], 1);
    }
    if (t < N) {
        int c = (cellc(q[3*t+2]) * GD + cellc(q[3*t+1])) * GD + cellc(q[3*t]);
        atomicAdd(&qcnt[c], 1);
    }
}

// ---- K2: prefix. block0: rcnt -> cmeta(off,cnt) + rpos. block1: qcnt -> qpos ----
__global__ __launch_bounds__(1024) void prefix_kern(const int* __restrict__ rcnt,
        int2* __restrict__ cmeta, int* __restrict__ rpos,
        const int* __restrict__ qcnt, int* __restrict__ qpos) {
    __shared__ int lds[1024];
    const int CH = NCELL / 1024;   // 108
    int tid = threadIdx.x;
    const int* src = (blockIdx.x == 0) ? rcnt : qcnt;
    int base = tid * CH;
    int sum = 0;
    for (int i = 0; i < CH; i++) sum += src[base + i];
    lds[tid] = sum; __syncthreads();
    for (int o = 1; o < 1024; o <<= 1) {
        int v = (tid >= o) ? lds[tid - o] : 0;
        __syncthreads();
        lds[tid] += v;
        __syncthreads();
    }
    int run = (tid == 0) ? 0 : lds[tid - 1];
    for (int i = 0; i < CH; i++) {
        int c = base + i;
        int n = src[c];
        if (blockIdx.x == 0) { cmeta[c] = make_int2(run, n); rpos[c] = run; }
        else                 { qpos[c] = run; }
        run += n;
    }
}

// ---- K3: scatter refs into cell-sorted copy; queries into cell-sorted id list ----
__global__ __launch_bounds__(256) void scatter_kern(const float* __restrict__ r,
        const float* __restrict__ q, int M, int N,
        int* __restrict__ rpos, int* __restrict__ qpos,
        float4* __restrict__ rpc, int* __restrict__ rid, int* __restrict__ qlist) {
    int t = blockIdx.x * 256 + threadIdx.x;
    if (t < M) {
        float x = r[3*t], y = r[3*t+1], z = r[3*t+2];
        float r2 = x*x + y*y + z*z;               // same fp32 r2 as reference path
        int c = (cellc(z) * GD + cellc(y)) * GD + cellc(x);
        int s = atomicAdd(&rpos[c], 1);
        rpc[s] = make_float4(x, y, z, r2);
        rid[s] = t;
    }
    if (t < N) {
        int c = (cellc(q[3*t+2]) * GD + cellc(q[3*t+1])) * GD + cellc(q[3*t]);
        qlist[atomicAdd(&qpos[c], 1)] = t;
    }
}

// ---- K4: thread-per-query ring walk (queries cell-sorted -> waves walk same cells) ----
__global__ __launch_bounds__(64) void knn_cell(const float* __restrict__ q,
        const float* __restrict__ f, const float4* __restrict__ rpc,
        const int* __restrict__ rid, const int2* __restrict__ cmeta,
        const int* __restrict__ qlist, float* __restrict__ out, int N) {
    int t = blockIdx.x * 64 + threadIdx.x;
    if (t >= N) return;
    int qi = qlist[t];
    float qx = q[3*qi], qy = q[3*qi+1], qz = q[3*qi+2];
    float q2 = qx*qx + qy*qy + qz*qz;
    bool inb = (qx >= BLO && qx <= BHI && qy >= BLO && qy <= BHI && qz >= BLO && qz <= BHI);
    int hx = cellc(qx), hy = cellc(qy), hz = cellc(qz);

    u64 bk[KNN];
#pragma unroll
    for (int k = 0; k < KNN; k++) bk[k] = KEY_INIT;
    float thr = BIGF;

    for (int rho = 0; rho < GD; rho++) {
        if (rho >= 2) {   // ring-rho cells are at distance >= (rho-1)*BW (valid also for clamped pts)
            float b = (rho - 1) * BW;
            if (b * b > thr * 1.001f + 0.01f) break;   // slack >> fp error of d2 formula
        }
        int zlo = max(hz - rho, 0), zhi = min(hz + rho, GD - 1);
        for (int cz = zlo; cz <= zhi; cz++) {
            int rdz = abs(cz - hz);
            int ylo = max(hy - rho, 0), yhi = min(hy + rho, GD - 1);
            for (int cy = ylo; cy <= yhi; cy++) {
                int rdy = abs(cy - hy);
                int step = (rdz == rho || rdy == rho) ? 1 : 2 * rho;
                for (int cx = hx - rho; cx <= hx + rho; cx += step) {
                    if (cx < 0 || cx >= GD) continue;
                    int c = (cz * GD + cy) * GD + cx;
                    int2 m = cmeta[c];                 // wave-near-uniform -> L1 broadcast
                    if (m.y == 0) continue;
                    if (inb) {                         // AABB prune valid only for in-box q
                        float bx = BLO + cx * BW;
                        float by = BLO + cy * BW;
                        float bz = BLO + cz * BW;
                        float dx = fmaxf(fmaxf(bx - qx, qx - (bx + BW)), 0.f);
                        float dy = fmaxf(fmaxf(by - qy, qy - (by + BW)), 0.f);
                        float dz = fmaxf(fmaxf(bz - qz, qz - (bz + BW)), 0.f);
                        float md = dx*dx + dy*dy + dz*dz;
                        if (md > thr * 1.001f + 0.01f) continue;
                    }
                    for (int s = m.x; s < m.x + m.y; s++) {
                        float4 p = rpc[s];
                        // EXACT reference numerics: (q2 + r2) - 2*(q . r), then max(.,0)
                        float d2 = (q2 + p.w) - 2.0f * (qx*p.x + qy*p.y + qz*p.z);
                        float d2c = fmaxf(d2, 0.0f);
                        if (d2c <= thr) {
                            ins8(((u64)__float_as_uint(d2c) << 32) | (u32)rid[s], bk);
                            thr = __uint_as_float((u32)(bk[0] >> 32));
                        }
                    }
                }
            }
        }
    }
    float wsum = 0.f, ox = 0.f, oy = 0.f, oz = 0.f;
#pragma unroll
    for (int k = 0; k < KNN; k++) {
        float d2c = __uint_as_float((u32)(bk[k] >> 32));
        int j = (int)(u32)bk[k];
        float wt = 1.0f / (d2c + EPSW);
        wsum += wt;
        ox += wt * f[3*j]; oy += wt * f[3*j+1]; oz += wt * f[3*j+2];
    }
    float invw = 1.0f / wsum;
    out[3*qi] = ox * invw; out[3*qi+1] = oy * invw; out[3*qi+2] = oz * invw;
}

// ---------- fallback (ws too small / tiny M): fused brute force (R6-proven) ----------
__global__ __launch_bounds__(256) void knn_fused(const float* __restrict__ q,
        const float* __restrict__ r, const float* __restrict__ f,
        float* __restrict__ out, int N, int M) {
    __shared__ float4 lds[2048];
    int qi = blockIdx.x * 256 + threadIdx.x;
    float qx = 0, qy = 0, qz = 0, q2 = 0;
    if (qi < N) { qx = q[3*qi]; qy = q[3*qi+1]; qz = q[3*qi+2]; q2 = qx*qx+qy*qy+qz*qz; }
    u64 bk[KNN];
#pragma unroll
    for (int k = 0; k < KNN; k++) bk[k] = KEY_INIT;
    float thr = BIGF;
    for (int tb = 0; tb < M; tb += 2048) {
        int cnt = min(2048, M - tb);
        for (int i = threadIdx.x; i < cnt; i += 256) {
            int j = tb + i;
            float rx = r[3*j], ry = r[3*j+1], rz = r[3*j+2];
            lds[i] = make_float4(rx, ry, rz, rx*rx + ry*ry + rz*rz);
        }
        __syncthreads();
        for (int i = 0; i < cnt; i++) {
            float4 p = lds[i];
            float d2 = (q2 + p.w) - 2.0f * (qx*p.x + qy*p.y + qz*p.z);
            float d2c = fmaxf(d2, 0.0f);
            if (d2c <= thr) {
                ins8(((u64)__float_as_uint(d2c) << 32) | (u32)(tb + i), bk);
                thr = __uint_as_float((u32)(bk[0] >> 32));
            }
        }
        __syncthreads();
    }
    if (qi < N) {
        float wsum = 0.f, ox = 0.f, oy = 0.f, oz = 0.f;
#pragma unroll
        for (int k = 0; k < KNN; k++) {
            float d2c = __uint_as_float((u32)(bk[k] >> 32));
            int j = (int)(u32)bk[k];
            float wt = 1.0f / (d2c + EPSW);
            wsum += wt;
            ox += wt * f[3*j]; oy += wt * f[3*j+1]; oz += wt * f[3*j+2];
        }
        float invw = 1.0f / wsum;
        out[3*qi] = ox*invw; out[3*qi+1] = oy*invw; out[3*qi+2] = oz*invw;
    }
}

extern "C" void kernel_launch(void* const* d_in, const int* in_sizes, int n_in,
                              void* d_out, int out_size, void* d_ws, size_t ws_size,
                              hipStream_t stream) {
    const float* q = (const float*)d_in[0];
    const float* r = (const float*)d_in[1];
    const float* f = (const float*)d_in[2];
    float* out = (float*)d_out;
    int N = in_sizes[0] / 3;
    int M = in_sizes[1] / 3;

    size_t offb = 0;
    auto alloc = [&](size_t bytes) { size_t o = offb; offb += (bytes + 15) & ~(size_t)15; return o; };
    size_t oRcnt = alloc((size_t)NCELL * 4);      // memset region: rcnt + qcnt contiguous
    size_t oQcnt = alloc((size_t)NCELL * 4);
    size_t oMeta = alloc((size_t)NCELL * 8);
    size_t oRpos = alloc((size_t)NCELL * 4);
    size_t oQpos = alloc((size_t)NCELL * 4);
    size_t oRpc  = alloc((size_t)M * 16);
    size_t oRid  = alloc((size_t)M * 4);
    size_t oQl   = alloc((size_t)N * 4);

    if (offb > ws_size || M < KNN) {
        knn_fused<<<(N + 255) / 256, 256, 0, stream>>>(q, r, f, out, N, M);
        return;
    }
    char* ws = (char*)d_ws;
    int*    rcnt = (int*)(ws + oRcnt);
    int*    qcnt = (int*)(ws + oQcnt);
    int2*   meta = (int2*)(ws + oMeta);
    int*    rpos = (int*)(ws + oRpos);
    int*    qpos = (int*)(ws + oQpos);
    float4* rpc  = (float4*)(ws + oRpc);
    int*    rid  = (int*)(ws + oRid);
    int*    qlist= (int*)(ws + oQl);

    hipMemsetAsync(ws + oRcnt, 0, (size_t)NCELL * 8, stream);
    int g = (max(N, M) + 255) / 256;
    count_kern<<<g, 256, 0, stream>>>(r, q, M, N, rcnt, qcnt);
    prefix_kern<<<2, 1024, 0, stream>>>(rcnt, meta, rpos, qcnt, qpos);
    scatter_kern<<<g, 256, 0, stream>>>(r, q, M, N, rpos, qpos, rpc, rid, qlist);
    knn_cell<<<(N + 63) / 64, 64, 0, stream>>>(q, f, rpc, rid, meta, qlist, out, N);
}